// Round 4
// baseline (957.599 us; speedup 1.0000x reference)
//
#include <hip/hip_runtime.h>
#include <hip/hip_bf16.h>
#include <stdint.h>

// ---------------------------------------------------------------------------
// R3: fused head kernel — per (64-row m-tile, head) block computes
// z = relu(feats@HW1[h]+b) in 4 chunks of 128 cols (K=1024 MFMA GEMM into
// regs), round-trips each chunk through padded LDS as bf16 A-fragments, and
// accumulates out = z@HW2[h]+Hb2 in a persistent 64x256 fp32 accumulator.
// z never touches HBM (saves ~384 MB round-trip + a dispatch).
// Trunk GEMMs + transposes unchanged from R2b.
// ---------------------------------------------------------------------------

typedef __bf16 bf16x8 __attribute__((ext_vector_type(8)));
typedef float  floatx4 __attribute__((ext_vector_type(4)));
typedef unsigned short ushortx4 __attribute__((ext_vector_type(4)));
typedef unsigned short ushortx8 __attribute__((ext_vector_type(8)));

typedef __attribute__((address_space(1))) void as1_void;
typedef __attribute__((address_space(3))) void as3_void;

__device__ __forceinline__ void gld_lds16(const void* g, void* l) {
    __builtin_amdgcn_global_load_lds((as1_void*)g, (as3_void*)l, 16, 0, 0);
}

__device__ __forceinline__ unsigned short f2bf(float f) {
    __hip_bfloat16 h = __float2bfloat16(f);
    unsigned short s;
    __builtin_memcpy(&s, &h, 2);
    return s;
}

// ---------------------------------------------------------------------------
// Trunk GEMM (MODE 0 only now):
// out = relu((acc + b - mean)*gamma*rsqrt(var+eps) + beta) -> bf16
// ---------------------------------------------------------------------------
__global__ __launch_bounds__(256, 2)
void gemm_bt(const short* __restrict__ A, int lda,
             const short* __restrict__ B, int ldb,
             short* __restrict__ C, int ldc,
             int K, int ntilesN,
             const float* __restrict__ p0, const float* __restrict__ p1,
             const float* __restrict__ p2, const float* __restrict__ p3,
             const float* __restrict__ p4)
{
    __shared__ short As[128 * 32];
    __shared__ short Bs[128 * 32];

    const int tid  = threadIdx.x;
    const int w    = tid >> 6;
    const int l    = tid & 63;
    const int mt   = blockIdx.x / ntilesN;
    const int nt   = blockIdx.x % ntilesN;
    const int m0   = mt * 128;
    const int n0   = nt * 128;

    const int wm   = (w >> 1) * 64;
    const int wn   = (w & 1) * 64;
    const int lrow = l & 15;
    const int lk   = (l >> 4) * 8;

    floatx4 acc[4][4] = {};

    const int srow = l >> 2;
    const int scol = (l & 3) * 8;
    const short* Ag = A + (long)(m0 + w * 16 + srow) * lda + scol;
    const short* Bg = B + (long)(n0 + w * 16 + srow) * ldb + scol;
    const long a64 = (long)64 * lda;
    const long b64 = (long)64 * ldb;
    short* AsW0 = &As[(w * 16) * 32];
    short* AsW1 = &As[(64 + w * 16) * 32];
    short* BsW0 = &Bs[(w * 16) * 32];
    short* BsW1 = &Bs[(64 + w * 16) * 32];

    for (int k0 = 0; k0 < K; k0 += 32) {
        gld_lds16(Ag + k0,       AsW0);
        gld_lds16(Ag + a64 + k0, AsW1);
        gld_lds16(Bg + k0,       BsW0);
        gld_lds16(Bg + b64 + k0, BsW1);
        __syncthreads();

        bf16x8 af[4], bfr[4];
#pragma unroll
        for (int i = 0; i < 4; ++i)
            af[i] = *(const bf16x8*)&As[(wm + i * 16 + lrow) * 32 + lk];
#pragma unroll
        for (int j = 0; j < 4; ++j)
            bfr[j] = *(const bf16x8*)&Bs[(wn + j * 16 + lrow) * 32 + lk];

#pragma unroll
        for (int i = 0; i < 4; ++i)
#pragma unroll
            for (int j = 0; j < 4; ++j)
                acc[i][j] = __builtin_amdgcn_mfma_f32_16x16x32_bf16(
                    af[i], bfr[j], acc[i][j], 0, 0, 0);
        __syncthreads();
    }

    const int erow = (l >> 4) * 4;
    const int ecol = l & 15;
#pragma unroll
    for (int j = 0; j < 4; ++j) {
        const int nj = n0 + wn + j * 16 + ecol;
        const float s = p1[nj] * rsqrtf(p4[nj] + 1e-5f);
        const float shift = (p0[nj] - p3[nj]) * s + p2[nj];
#pragma unroll
        for (int i = 0; i < 4; ++i) {
            const long mi = m0 + wm + i * 16 + erow;
#pragma unroll
            for (int r = 0; r < 4; ++r) {
                float v = fmaxf(acc[i][j][r] * s + shift, 0.f);
                C[(mi + r) * (long)ldc + nj] = (short)f2bf(v);
            }
        }
    }
}

// ---------------------------------------------------------------------------
// Fused heads: block = (mtile of 64 feats rows, head). 256 threads, 4 waves.
// out[64 x 256] = relu(feats[64x1024] @ HW1T[h]^T + Hb1) @ HW2T[h]^T + Hb2
// ---------------------------------------------------------------------------
__global__ __launch_bounds__(256, 3)
void fused_heads(const short* __restrict__ feats,      // [1024][1024] bf16
                 const short* __restrict__ HW1T,       // [128][512][1024] bf16
                 const short* __restrict__ HW2T,       // [128][256][512] bf16
                 const float* __restrict__ Hb1,        // [128][512]
                 const float* __restrict__ Hb2,        // [128][256]
                 float* __restrict__ out)              // [1024][128][256]
{
    __shared__ short As[64 * 32];     //  4 KB  feats tile
    __shared__ short Bs[128 * 32];    //  8 KB  HW1T tile
    __shared__ short B2s[256 * 32];   // 16 KB  HW2T tile
    __shared__ short zs[64 * 136];    // 17 KB  z chunk (padded: stride 136)

    const int tid  = threadIdx.x;
    const int w    = tid >> 6;
    const int l    = tid & 63;
    const int mt   = blockIdx.x;
    const int head = blockIdx.y;
    const int m0   = mt * 64;

    const int lrow = l & 15;
    const int lk   = (l >> 4) * 8;
    const int erow = (l >> 4) * 4;
    const int ecol = l & 15;

    const short* W1h = HW1T + (long)head * 512 * 1024;
    const short* W2h = HW2T + (long)head * 256 * 512;

    const int srow = l >> 2;          // staging row within 16-row chunk
    const int scol = (l & 3) * 8;     // staging k offset (elements)

    const short* AgBase  = feats + (long)(m0 + w * 16 + srow) * 1024 + scol;
    short* AsW = &As[(w * 16) * 32];

    floatx4 acc2[4][4] = {};          // persistent out accumulator 64x256

    for (int c = 0; c < 4; ++c) {
        // ---- phase 1: zc[64 x 128] = feats[64x1024] @ W1h[c*128..+128][:]^T
        floatx4 acc1[4][2] = {};
        const short* BgBase = W1h + (long)(c * 128 + w * 16 + srow) * 1024 + scol;
        short* BsW0 = &Bs[(w * 16) * 32];
        short* BsW1 = &Bs[(64 + w * 16) * 32];

        for (int k0 = 0; k0 < 1024; k0 += 32) {
            gld_lds16(AgBase + k0,               AsW);
            gld_lds16(BgBase + k0,               BsW0);
            gld_lds16(BgBase + (long)64 * 1024 + k0, BsW1);
            __syncthreads();

            bf16x8 af[4], bfr[2];
#pragma unroll
            for (int i = 0; i < 4; ++i)
                af[i] = *(const bf16x8*)&As[(i * 16 + lrow) * 32 + lk];
#pragma unroll
            for (int j = 0; j < 2; ++j)
                bfr[j] = *(const bf16x8*)&Bs[(w * 32 + j * 16 + lrow) * 32 + lk];

#pragma unroll
            for (int i = 0; i < 4; ++i)
#pragma unroll
                for (int j = 0; j < 2; ++j)
                    acc1[i][j] = __builtin_amdgcn_mfma_f32_16x16x32_bf16(
                        af[i], bfr[j], acc1[i][j], 0, 0, 0);
            __syncthreads();
        }

        // ---- z chunk -> LDS (relu + bias, bf16), A-fragment-friendly layout
#pragma unroll
        for (int j = 0; j < 2; ++j) {
            const int kz = w * 32 + j * 16 + ecol;            // 0..127
            const float bias = Hb1[head * 512 + c * 128 + kz];
#pragma unroll
            for (int i = 0; i < 4; ++i) {
                const int mrow = i * 16 + erow;
#pragma unroll
                for (int r = 0; r < 4; ++r) {
                    const float v = fmaxf(acc1[i][j][r] + bias, 0.f);
                    zs[(mrow + r) * 136 + kz] = (short)f2bf(v);
                }
            }
        }

        // ---- phase 2: acc2 += zc[64x128] @ W2h[:, c*128..+128]^T
        for (int kk = 0; kk < 4; ++kk) {
            const short* B2g = W2h + (long)(w * 16 + srow) * 512 + c * 128 + kk * 32 + scol;
#pragma unroll
            for (int q = 0; q < 4; ++q)
                gld_lds16(B2g + (long)q * 64 * 512, &B2s[(q * 64 + w * 16) * 32]);
            __syncthreads();

            bf16x8 af2[4], bf2[4];
#pragma unroll
            for (int i = 0; i < 4; ++i)
                af2[i] = *(const bf16x8*)&zs[(i * 16 + lrow) * 136 + kk * 32 + lk];
#pragma unroll
            for (int j = 0; j < 4; ++j)
                bf2[j] = *(const bf16x8*)&B2s[(w * 64 + j * 16 + lrow) * 32 + lk];

#pragma unroll
            for (int i = 0; i < 4; ++i)
#pragma unroll
                for (int j = 0; j < 4; ++j)
                    acc2[i][j] = __builtin_amdgcn_mfma_f32_16x16x32_bf16(
                        af2[i], bf2[j], acc2[i][j], 0, 0, 0);
            __syncthreads();
        }
    }

    // ---- epilogue: out[(m0+m)*128*256 + head*256 + n2] = acc2 + Hb2
#pragma unroll
    for (int j = 0; j < 4; ++j) {
        const int n2 = w * 64 + j * 16 + ecol;
        const float bias = Hb2[head * 256 + n2];
#pragma unroll
        for (int i = 0; i < 4; ++i) {
            const long mi = m0 + i * 16 + erow;
#pragma unroll
            for (int r = 0; r < 4; ++r)
                out[(mi + r) * (long)(128 * 256) + head * 256 + n2] =
                    acc2[i][j][r] + bias;
        }
    }
}

// ---------------------------------------------------------------------------
// Fast fp32 [R][C] -> bf16 [C][R] transpose, R and C multiples of 64, batched.
// ---------------------------------------------------------------------------
__global__ __launch_bounds__(256)
void transpose64(const float* __restrict__ in, unsigned short* __restrict__ out,
                 int R, int C, long inBatch, long outBatch)
{
    __shared__ unsigned short lt[64 * 68];
    in  += (long)blockIdx.z * inBatch;
    out += (long)blockIdx.z * outBatch;
    const int c0 = blockIdx.x * 64;
    const int r0 = blockIdx.y * 64;
    const int t  = threadIdx.x;

    {
        const int rb = t >> 4;
        const int cg = (t & 15) * 4;
        floatx4 v[4];
#pragma unroll
        for (int i = 0; i < 4; ++i)
            v[i] = *(const floatx4*)&in[(long)(r0 + rb * 4 + i) * C + c0 + cg];
#pragma unroll
        for (int j = 0; j < 4; ++j) {
            ushortx4 col;
#pragma unroll
            for (int i = 0; i < 4; ++i) col[i] = f2bf(v[i][j]);
            *(ushortx4*)&lt[(cg + j) * 68 + rb * 4] = col;
        }
    }
    __syncthreads();

#pragma unroll
    for (int it = 0; it < 2; ++it) {
        const int idx = t + it * 256;
        const int c   = idx >> 3;
        const int rc  = idx & 7;
        ushortx4 lo = *(const ushortx4*)&lt[c * 68 + rc * 8];
        ushortx4 hi = *(const ushortx4*)&lt[c * 68 + rc * 8 + 4];
        ushortx8 o;
        o[0] = lo[0]; o[1] = lo[1]; o[2] = lo[2]; o[3] = lo[3];
        o[4] = hi[0]; o[5] = hi[1]; o[6] = hi[2]; o[7] = hi[3];
        *(ushortx8*)&out[(long)(c0 + c) * R + r0 + rc * 8] = o;
    }
}

// slow-path transpose (tiny W0, R=200 -> Rpad=224)
__global__ void transpose_f32_bf16(const float* __restrict__ in, short* __restrict__ out,
                                   int R, int C, int Rpad, long inBatch, long outBatch)
{
    __shared__ float tile[32][33];
    in  += (long)blockIdx.z * inBatch;
    out += (long)blockIdx.z * outBatch;
    const int c0 = blockIdx.x * 32;
    const int r0 = blockIdx.y * 32;
    const int tx = threadIdx.x, ty = threadIdx.y;
#pragma unroll
    for (int rr = 0; rr < 4; ++rr) {
        const int r = r0 + ty + rr * 8;
        float v = 0.f;
        if (r < R) v = in[(long)r * C + c0 + tx];
        tile[ty + rr * 8][tx] = v;
    }
    __syncthreads();
#pragma unroll
    for (int rr = 0; rr < 4; ++rr) {
        const int oc = ty + rr * 8;
        out[(long)(c0 + oc) * Rpad + r0 + tx] = (short)f2bf(tile[tx][oc]);
    }
}

__global__ void pad_convert(const float* __restrict__ in, short* __restrict__ out,
                            int C, int Cpad, int total)
{
    const int idx = blockIdx.x * 256 + threadIdx.x;
    if (idx >= total) return;
    const int r = idx / Cpad, c = idx % Cpad;
    out[idx] = (short)f2bf(c < C ? in[(long)r * C + c] : 0.f);
}

// ---------------------------------------------------------------------------

extern "C" void kernel_launch(void* const* d_in, const int* in_sizes, int n_in,
                              void* d_out, int out_size, void* d_ws, size_t ws_size,
                              hipStream_t stream)
{
    const float* x   = (const float*)d_in[0];
    const float* W0  = (const float*)d_in[1];
    const float* b0  = (const float*)d_in[2];
    const float* g0  = (const float*)d_in[3];
    const float* be0 = (const float*)d_in[4];
    const float* m0  = (const float*)d_in[5];
    const float* v0  = (const float*)d_in[6];
    const float* W1  = (const float*)d_in[7];
    const float* b1  = (const float*)d_in[8];
    const float* g1  = (const float*)d_in[9];
    const float* be1 = (const float*)d_in[10];
    const float* m1  = (const float*)d_in[11];
    const float* v1  = (const float*)d_in[12];
    const float* HW1 = (const float*)d_in[13];
    const float* Hb1 = (const float*)d_in[14];
    const float* HW2 = (const float*)d_in[15];
    const float* Hb2 = (const float*)d_in[16];
    float* out = (float*)d_out;

    char* ws = (char*)d_ws;
    size_t off = 0;
    short* xb   = (short*)(ws + off); off += (size_t)1024 * 224 * 2;
    short* W0T  = (short*)(ws + off); off += (size_t)2048 * 224 * 2;
    short* W1T  = (short*)(ws + off); off += (size_t)1024 * 2048 * 2;
    short* HW1T = (short*)(ws + off); off += (size_t)128 * 512 * 1024 * 2;
    short* HW2T = (short*)(ws + off); off += (size_t)128 * 256 * 512 * 2;
    short* h    = (short*)(ws + off); off += (size_t)1024 * 2048 * 2;
    short* fts  = (short*)(ws + off); off += (size_t)1024 * 1024 * 2;

    // bf16 conversions / transposes
    pad_convert<<<dim3((1024 * 224) / 256), dim3(256), 0, stream>>>(x, xb, 200, 224, 1024 * 224);
    transpose_f32_bf16<<<dim3(64, 7, 1), dim3(32, 8), 0, stream>>>(W0, W0T, 200, 2048, 224, 0, 0);
    transpose64<<<dim3(16, 32, 1), dim3(256), 0, stream>>>(
        W1, (unsigned short*)W1T, 2048, 1024, 0, 0);
    transpose64<<<dim3(8, 16, 128), dim3(256), 0, stream>>>(
        HW1, (unsigned short*)HW1T, 1024, 512, (long)1024 * 512, (long)512 * 1024);
    transpose64<<<dim3(4, 8, 128), dim3(256), 0, stream>>>(
        HW2, (unsigned short*)HW2T, 512, 256, (long)512 * 256, (long)256 * 512);

    // trunk: h = relu(BN0(x@W0 + b0))   M=1024 N=2048 K=224
    gemm_bt<<<dim3(8 * 16), dim3(256), 0, stream>>>(
        xb, 224, W0T, 224, h, 2048, 224, 16, b0, g0, be0, m0, v0);
    // trunk: feats = relu(BN1(h@W1 + b1))   M=1024 N=1024 K=2048
    gemm_bt<<<dim3(8 * 8), dim3(256), 0, stream>>>(
        h, 2048, W1T, 2048, fts, 1024, 2048, 8, b1, g1, be1, m1, v1);
    // fused heads: out = relu(feats@HW1+Hb1)@HW2 + Hb2
    fused_heads<<<dim3(16, 128), dim3(256), 0, stream>>>(
        fts, HW1T, HW2T, Hb1, Hb2, out);

    (void)in_sizes; (void)n_in; (void)out_size; (void)ws_size;
}